// Round 1
// baseline (1472.353 us; speedup 1.0000x reference)
//
#include <hip/hip_runtime.h>

typedef unsigned short u16;
typedef __bf16 bf16x8 __attribute__((ext_vector_type(8)));
typedef unsigned short u16x8 __attribute__((ext_vector_type(8)));
typedef unsigned short u16x4 __attribute__((ext_vector_type(4)));
typedef float f32x4 __attribute__((ext_vector_type(4)));

#define K_DIM 2048

// async global->LDS, 16B per lane; lds ptr must be wave-uniform base (+lane*16 in HW)
#define GLL16(g, l) __builtin_amdgcn_global_load_lds( \
    (const __attribute__((address_space(1))) void*)(g), \
    (__attribute__((address_space(3))) void*)(l), 16, 0, 0)

// phase barrier: compiler memory fence + hw barrier + fence (keeps LDS/GLL ops inside their phase)
#define PHB() do { asm volatile("" ::: "memory"); __builtin_amdgcn_s_barrier(); asm volatile("" ::: "memory"); } while (0)
#define VMW(n) asm volatile("s_waitcnt vmcnt(" #n ")" ::: "memory")
#define MFMA_(av, bv, cc) (cc) = __builtin_amdgcn_mfma_f32_16x16x32_bf16((av), (bv), (cc), 0, 0, 0)

__device__ __forceinline__ u16 f2bf(float f) {
    unsigned int u = __builtin_bit_cast(unsigned int, f);
    u = (u + 0x7fffu + ((u >> 16) & 1u)) >> 16;   // RNE
    return (u16)u;
}
__device__ __forceinline__ float bf2f(u16 h) {
    unsigned int u = ((unsigned int)h) << 16;
    return __builtin_bit_cast(float, u);
}
__device__ __forceinline__ float softplus_f(float v) {
    return fmaxf(v, 0.0f) + log1pf(expf(-fabsf(v)));
}

// ---------------- pack f32 -> bf16, 4 elems/thread ----------------
__global__ void pack_kernel(const float* __restrict__ src, u16* __restrict__ dst, int n4) {
    int i = blockIdx.x * blockDim.x + threadIdx.x;
    if (i >= n4) return;
    float4 v = ((const float4*)src)[i];
    u16x4 o;
    o[0] = f2bf(v.x); o[1] = f2bf(v.y); o[2] = f2bf(v.z); o[3] = f2bf(v.w);
    ((u16x4*)dst)[i] = o;
}

// ---------------- fused GEMM: C = A * B^T, 256x256 tile, BK=64, 8-phase schedule ----------------
// LDS layout per buffer per matrix: [2 kslices][16 groups of 16 rows][64 chunks of 16B],
// chunk (row r, q) of a k-slice stored at in-group position (r&15)*4 + ((q + ((r&15)>>1))&3)
// (same XOR/add swizzle as the proven 128^2 kernel -> 0 bank conflicts on ds_read_b128).
//
// Phase schedule per iteration (2 K-tiles: even->buf0 computed ph1-4, odd->buf1 computed ph5-8):
//   ph1: read A[0..3],B[0..1] (buf0); stage A-ks0 -> buf1 (tile 2i+1); MFMA acc[0..3][0..1]
//   ph2: read B[2..3] (buf0);         stage A-ks1 -> buf1;             MFMA acc[0..3][2..3]
//   ph3: read A[4..7] (buf0);         stage B-ks0 -> buf0 (tile 2i+2); MFMA acc[4..7][2..3]
//   ph4:                              stage B-ks1 -> buf0; MFMA acc[4..7][0..1]; vmcnt(4)
//   ph5..ph8: same with buf0<->buf1 swapped, A->buf0 (2i+2), B->buf1 (2i+3); vmcnt(4) at ph8
// vmcnt(4) leaves the 2 newest part-loads in flight; the 8 drained are exactly the buffer
// read in the next 4 phases. WAR: every staged region's last read is >=1 barrier earlier.
__global__ __launch_bounds__(512, 2) void gemm_fused(
    const u16* __restrict__ xb, const u16* __restrict__ wb,
    u16* __restrict__ qb, u16* __restrict__ kb,
    u16* __restrict__ sqb, u16* __restrict__ skb)
{
    __shared__ __align__(16) u16 Als[32768];   // 2 bufs x 16384 u16 (32KB each)
    __shared__ __align__(16) u16 Bls[32768];
    __shared__ float ss[512];                  // [2 head-halves][256 rows]

    const int tid  = threadIdx.x;
    const int lane = tid & 63;
    const int wave = tid >> 6;
    const int wm   = wave >> 2;     // 2 waves in M
    const int wn   = wave & 3;      // 4 waves in N
    const int gm0  = blockIdx.y * 256;
    const int gn0  = blockIdx.x * 256;

    // staging: load l covers (kslice, row-group) G = l*8+wave; lane -> row g*16+(lane>>2),
    // in-group slot lane (pos j=lane&3) must receive source chunk q=(j-(pr>>1))&3.
    const int q8 = (((lane & 3) - ((lane >> 3) & 3)) & 3) * 8;
    int offS[4]; const u16* pa[4]; const u16* pb[4];
#pragma unroll
    for (int l = 0; l < 4; ++l) {
        const int G = l * 8 + wave;
        const int s = G >> 4, g = G & 15;
        offS[l] = s * 8192 + g * 512;                   // u16 offset within one buffer
        const int r = g * 16 + (lane >> 2);
        pa[l] = xb + (size_t)(gm0 + r) * K_DIM + s * 32 + q8;
        pb[l] = wb + (size_t)(gn0 + r) * K_DIM + s * 32 + q8;
    }

    // read side: lane holds row mr=lane&15, k-chunk qh=lane>>4 at swizzled pos
    const int mr  = lane & 15;
    const int srd = ((lane >> 4) + (mr >> 1)) & 3;
    const int fro = mr * 32 + srd * 8;
    const int aRB = wm * 8 * 512 + fro;    // A groups wm*8 + i
    const int bRB = wn * 4 * 512 + fro;    // B groups wn*4 + j

    f32x4 acc[8][4] = {};

    // prologue: tile0 (A,B) -> buf0, tile1 B -> buf1; drain + barrier
#pragma unroll
    for (int l = 0; l < 4; ++l) GLL16(pa[l], &Als[offS[l]]);
#pragma unroll
    for (int l = 0; l < 4; ++l) GLL16(pb[l], &Bls[offS[l]]);
#pragma unroll
    for (int l = 0; l < 4; ++l) GLL16(pb[l] + 64, &Bls[16384 + offS[l]]);
    __syncthreads();

#define LDA(buf, i, ks) __builtin_bit_cast(bf16x8, *(const u16x8*)&Als[(buf)*16384 + (ks)*8192 + aRB + (i)*512])
#define LDB(buf, j, ks) __builtin_bit_cast(bf16x8, *(const u16x8*)&Bls[(buf)*16384 + (ks)*8192 + bRB + (j)*512])

    for (int it = 0; it < 16; ++it) {
        bf16x8 a03[4][2], a47[4][2], b01[2][2], b23[2][2];

        // ---- ph1 ----
#pragma unroll
        for (int i = 0; i < 4; ++i) { a03[i][0] = LDA(0, i, 0); a03[i][1] = LDA(0, i, 1); }
#pragma unroll
        for (int j = 0; j < 2; ++j) { b01[j][0] = LDB(0, j, 0); b01[j][1] = LDB(0, j, 1); }
        GLL16(pa[0] + 64, &Als[16384 + offS[0]]);
        GLL16(pa[1] + 64, &Als[16384 + offS[1]]);
        PHB();
        __builtin_amdgcn_s_setprio(1);
#pragma unroll
        for (int i = 0; i < 4; ++i) {
            MFMA_(a03[i][0], b01[0][0], acc[i][0]); MFMA_(a03[i][1], b01[0][1], acc[i][0]);
            MFMA_(a03[i][0], b01[1][0], acc[i][1]); MFMA_(a03[i][1], b01[1][1], acc[i][1]);
        }
        __builtin_amdgcn_s_setprio(0);
        PHB();

        // ---- ph2 ----
#pragma unroll
        for (int j = 0; j < 2; ++j) { b23[j][0] = LDB(0, j + 2, 0); b23[j][1] = LDB(0, j + 2, 1); }
        GLL16(pa[2] + 64, &Als[16384 + offS[2]]);
        GLL16(pa[3] + 64, &Als[16384 + offS[3]]);
        PHB();
        __builtin_amdgcn_s_setprio(1);
#pragma unroll
        for (int i = 0; i < 4; ++i) {
            MFMA_(a03[i][0], b23[0][0], acc[i][2]); MFMA_(a03[i][1], b23[0][1], acc[i][2]);
            MFMA_(a03[i][0], b23[1][0], acc[i][3]); MFMA_(a03[i][1], b23[1][1], acc[i][3]);
        }
        __builtin_amdgcn_s_setprio(0);
        PHB();

        // ---- ph3 ----
#pragma unroll
        for (int i = 0; i < 4; ++i) { a47[i][0] = LDA(0, i + 4, 0); a47[i][1] = LDA(0, i + 4, 1); }
        GLL16(pb[0] + 128, &Bls[offS[0]]);
        GLL16(pb[1] + 128, &Bls[offS[1]]);
        PHB();
        __builtin_amdgcn_s_setprio(1);
#pragma unroll
        for (int i = 0; i < 4; ++i) {
            MFMA_(a47[i][0], b23[0][0], acc[4 + i][2]); MFMA_(a47[i][1], b23[0][1], acc[4 + i][2]);
            MFMA_(a47[i][0], b23[1][0], acc[4 + i][3]); MFMA_(a47[i][1], b23[1][1], acc[4 + i][3]);
        }
        __builtin_amdgcn_s_setprio(0);
        PHB();

        // ---- ph4 ----
        GLL16(pb[2] + 128, &Bls[offS[2]]);
        GLL16(pb[3] + 128, &Bls[offS[3]]);
        PHB();
        __builtin_amdgcn_s_setprio(1);
#pragma unroll
        for (int i = 0; i < 4; ++i) {
            MFMA_(a47[i][0], b01[0][0], acc[4 + i][0]); MFMA_(a47[i][1], b01[0][1], acc[4 + i][0]);
            MFMA_(a47[i][0], b01[1][0], acc[4 + i][1]); MFMA_(a47[i][1], b01[1][1], acc[4 + i][1]);
        }
        __builtin_amdgcn_s_setprio(0);
        VMW(4);   // drains buf1 (A: ph1/2, B: prev ph7/8) before ph5 reads it
        PHB();

        // ---- ph5 ----
#pragma unroll
        for (int i = 0; i < 4; ++i) { a03[i][0] = LDA(1, i, 0); a03[i][1] = LDA(1, i, 1); }
#pragma unroll
        for (int j = 0; j < 2; ++j) { b01[j][0] = LDB(1, j, 0); b01[j][1] = LDB(1, j, 1); }
        GLL16(pa[0] + 128, &Als[offS[0]]);
        GLL16(pa[1] + 128, &Als[offS[1]]);
        PHB();
        __builtin_amdgcn_s_setprio(1);
#pragma unroll
        for (int i = 0; i < 4; ++i) {
            MFMA_(a03[i][0], b01[0][0], acc[i][0]); MFMA_(a03[i][1], b01[0][1], acc[i][0]);
            MFMA_(a03[i][0], b01[1][0], acc[i][1]); MFMA_(a03[i][1], b01[1][1], acc[i][1]);
        }
        __builtin_amdgcn_s_setprio(0);
        PHB();

        // ---- ph6 ----
#pragma unroll
        for (int j = 0; j < 2; ++j) { b23[j][0] = LDB(1, j + 2, 0); b23[j][1] = LDB(1, j + 2, 1); }
        GLL16(pa[2] + 128, &Als[offS[2]]);
        GLL16(pa[3] + 128, &Als[offS[3]]);
        PHB();
        __builtin_amdgcn_s_setprio(1);
#pragma unroll
        for (int i = 0; i < 4; ++i) {
            MFMA_(a03[i][0], b23[0][0], acc[i][2]); MFMA_(a03[i][1], b23[0][1], acc[i][2]);
            MFMA_(a03[i][0], b23[1][0], acc[i][3]); MFMA_(a03[i][1], b23[1][1], acc[i][3]);
        }
        __builtin_amdgcn_s_setprio(0);
        PHB();

        // ---- ph7 ----
#pragma unroll
        for (int i = 0; i < 4; ++i) { a47[i][0] = LDA(1, i + 4, 0); a47[i][1] = LDA(1, i + 4, 1); }
        GLL16(pb[0] + 192, &Bls[16384 + offS[0]]);
        GLL16(pb[1] + 192, &Bls[16384 + offS[1]]);
        PHB();
        __builtin_amdgcn_s_setprio(1);
#pragma unroll
        for (int i = 0; i < 4; ++i) {
            MFMA_(a47[i][0], b23[0][0], acc[4 + i][2]); MFMA_(a47[i][1], b23[0][1], acc[4 + i][2]);
            MFMA_(a47[i][0], b23[1][0], acc[4 + i][3]); MFMA_(a47[i][1], b23[1][1], acc[4 + i][3]);
        }
        __builtin_amdgcn_s_setprio(0);
        PHB();

        // ---- ph8 ----
        GLL16(pb[2] + 192, &Bls[16384 + offS[2]]);
        GLL16(pb[3] + 192, &Bls[16384 + offS[3]]);
        PHB();
        __builtin_amdgcn_s_setprio(1);
#pragma unroll
        for (int i = 0; i < 4; ++i) {
            MFMA_(a47[i][0], b01[0][0], acc[4 + i][0]); MFMA_(a47[i][1], b01[0][1], acc[4 + i][0]);
            MFMA_(a47[i][0], b01[1][0], acc[4 + i][1]); MFMA_(a47[i][1], b01[1][1], acc[4 + i][1]);
        }
        __builtin_amdgcn_s_setprio(0);
        VMW(4);   // drains buf0 (B: ph3/4, A: ph5/6) before next-iter ph1 reads it
        PHB();

#pragma unroll
        for (int l = 0; l < 4; ++l) { pa[l] += 128; pb[l] += 128; }
    }
    VMW(0);   // no GLL may land after this block's LDS is recycled

    // ---------------- epilogue ----------------
    const int which = gn0 >> 11;          // 0:q 1:k 2:sq 3:sk (block-uniform)
    ss[tid] = 0.0f;
    __syncthreads();

    const int h = wn >> 1;                // head-half within the 256-wide tile
    if (which < 2) {
#pragma unroll
        for (int i = 0; i < 8; ++i) {
#pragma unroll
            for (int r = 0; r < 4; ++r) {
                float sv = acc[i][0][r] * acc[i][0][r] + acc[i][1][r] * acc[i][1][r]
                         + acc[i][2][r] * acc[i][2][r] + acc[i][3][r] * acc[i][3][r];
                sv += __shfl_xor(sv, 1, 64);
                sv += __shfl_xor(sv, 2, 64);
                sv += __shfl_xor(sv, 4, 64);
                sv += __shfl_xor(sv, 8, 64);
                if ((lane & 15) == 0)
                    atomicAdd(&ss[h * 256 + wm * 128 + i * 16 + (lane >> 4) * 4 + r], sv);
            }
        }
        __syncthreads();
    }

    u16* ob = (which == 0) ? qb : (which == 1) ? kb : (which == 2) ? sqb : skb;
    const int col0 = (gn0 & 2047) + wn * 64 + (lane & 15);
#pragma unroll
    for (int i = 0; i < 8; ++i) {
#pragma unroll
        for (int r = 0; r < 4; ++r) {
            const int m = wm * 128 + i * 16 + (lane >> 4) * 4 + r;
            const size_t rowbase = (size_t)(gm0 + m) * 2048;
            float scale = 1.0f;
            if (which < 2)
                scale = rsqrtf(ss[h * 256 + m] * (1.0f / 128.0f) + 1.1920929e-07f);
#pragma unroll
            for (int j = 0; j < 4; ++j) {
                float v = acc[i][j][r];
                v = (which < 2) ? v * scale : softplus_f(v);
                ob[rowbase + col0 + j * 16] = f2bf(v);
            }
        }
    }
}

// ---------------- interp + multiply ----------------
__global__ void interp_mul(const u16* __restrict__ qb, const u16* __restrict__ kb,
                           const u16* __restrict__ sqb, const u16* __restrict__ skb,
                           float* __restrict__ out)
{
    size_t idx = (size_t)blockIdx.x * 256 + threadIdx.x;   // exact: 131072*256 = 2^25
    int c = (int)(idx & 2047);
    size_t bt = idx >> 11;
    int t = (int)(bt & 4095);
    float tf = (float)t;

    float sqv = bf2f(sqb[idx]);
    float skv = bf2f(skb[idx]);
    float pq = fminf(fmaxf(tf - sqv, 0.0f), tf);
    float pk = fminf(fmaxf(tf - skv, 0.0f), tf);
    float pqf = floorf(pq), pkf = floorf(pk);
    int q0i = (int)pqf, k0i = (int)pkf;
    int q1i = min(q0i + 1, 4095), k1i = min(k0i + 1, 4095);
    float fq = pq - pqf, fk = pk - pkf;

    size_t rb = (idx >> 23) << 23;   // b * T * 2048
    size_t o = rb + (size_t)c;
    float q0 = bf2f(qb[o + ((size_t)q0i << 11)]);
    float q1 = bf2f(qb[o + ((size_t)q1i << 11)]);
    float k0 = bf2f(kb[o + ((size_t)k0i << 11)]);
    float k1 = bf2f(kb[o + ((size_t)k1i << 11)]);
    float qd = q0 + (q1 - q0) * fq;
    float kd = k0 + (k1 - k0) * fk;
    out[idx] = qd * kd;
}

extern "C" void kernel_launch(void* const* d_in, const int* in_sizes, int n_in,
                              void* d_out, int out_size, void* d_ws, size_t ws_size,
                              hipStream_t stream) {
    const float* x   = (const float*)d_in[0];
    const float* Wq  = (const float*)d_in[1];
    const float* Wk  = (const float*)d_in[2];
    const float* Wsq = (const float*)d_in[3];
    const float* Wsk = (const float*)d_in[4];
    float* out = (float*)d_out;

    // ws layout (bytes): xb 64MB | wb 32MB | qb 64MB | kb 64MB | sqb 64MB | skb 64MB = 352MB
    const size_t NEED = 369098752;
    if (ws_size < NEED) return;
    char* ws = (char*)d_ws;
    u16* xb  = (u16*)(ws);
    u16* wb  = (u16*)(ws + 67108864);
    u16* qb  = (u16*)(ws + 100663296);
    u16* kb  = (u16*)(ws + 167772160);
    u16* sqb = (u16*)(ws + 234881024);
    u16* skb = (u16*)(ws + 301989888);

    pack_kernel<<<32768, 256, 0, stream>>>(x,   xb, 8388608);
    pack_kernel<<<4096,  256, 0, stream>>>(Wq,  wb,            1048576);
    pack_kernel<<<4096,  256, 0, stream>>>(Wk,  wb + 4194304,  1048576);
    pack_kernel<<<4096,  256, 0, stream>>>(Wsq, wb + 8388608,  1048576);
    pack_kernel<<<4096,  256, 0, stream>>>(Wsk, wb + 12582912, 1048576);

    dim3 ggrid(32, 64);   // N tiles x M tiles
    gemm_fused<<<ggrid, 512, 0, stream>>>(xb, wb, qb, kb, sqb, skb);

    interp_mul<<<131072, 256, 0, stream>>>(qb, kb, sqb, skb, out);
}

// Round 2
// 1200.509 us; speedup vs baseline: 1.2264x; 1.2264x over previous
//
#include <hip/hip_runtime.h>

typedef unsigned short u16;
typedef __bf16 bf16x8 __attribute__((ext_vector_type(8)));
typedef unsigned short u16x8 __attribute__((ext_vector_type(8)));
typedef unsigned short u16x4 __attribute__((ext_vector_type(4)));
typedef float f32x4 __attribute__((ext_vector_type(4)));

#define K_DIM 2048
#define BM 128
#define BN 128
#define BK 32

// async global->LDS, 16B per lane; lds ptr must be wave-uniform base (+lane*16 in HW)
#define GLL16(g, l) __builtin_amdgcn_global_load_lds( \
    (const __attribute__((address_space(1))) void*)(g), \
    (__attribute__((address_space(3))) void*)(l), 16, 0, 0)

__device__ __forceinline__ u16 f2bf(float f) {
    unsigned int u = __builtin_bit_cast(unsigned int, f);
    u = (u + 0x7fffu + ((u >> 16) & 1u)) >> 16;   // RNE
    return (u16)u;
}
__device__ __forceinline__ float bf2f(u16 h) {
    unsigned int u = ((unsigned int)h) << 16;
    return __builtin_bit_cast(float, u);
}
__device__ __forceinline__ float softplus_f(float v) {
    return fmaxf(v, 0.0f) + log1pf(expf(-fabsf(v)));
}

// ---------------- pack f32 -> bf16, 4 elems/thread ----------------
__global__ void pack_kernel(const float* __restrict__ src, u16* __restrict__ dst, int n4) {
    int i = blockIdx.x * blockDim.x + threadIdx.x;
    if (i >= n4) return;
    float4 v = ((const float4*)src)[i];
    u16x4 o;
    o[0] = f2bf(v.x); o[1] = f2bf(v.y); o[2] = f2bf(v.z); o[3] = f2bf(v.w);
    ((u16x4*)dst)[i] = o;
}

// ---- pack all 4 weight matrices in one launch: grid.y selects source ----
__global__ void pack4_kernel(const float* __restrict__ s0, const float* __restrict__ s1,
                             const float* __restrict__ s2, const float* __restrict__ s3,
                             u16* __restrict__ dst) {
    int i = blockIdx.x * blockDim.x + threadIdx.x;   // 0 .. 1048575 (float4 units)
    const float* src = (blockIdx.y == 0) ? s0 : (blockIdx.y == 1) ? s1
                     : (blockIdx.y == 2) ? s2 : s3;
    float4 v = ((const float4*)src)[i];
    u16x4 o;
    o[0] = f2bf(v.x); o[1] = f2bf(v.y); o[2] = f2bf(v.z); o[3] = f2bf(v.w);
    ((u16x4*)(dst + (size_t)blockIdx.y * 4194304))[i] = o;
}

// ---------------- fused GEMM: C = A * B^T with rms/softplus epilogue ----------------
// (proven 852us version: 128x128 tile, BK=32, XOR/add-swizzled LDS, 0 bank conflicts)
__global__ __launch_bounds__(256) void gemm_fused(
    const u16* __restrict__ xb, const u16* __restrict__ wb,
    u16* __restrict__ qb, u16* __restrict__ kb,
    u16* __restrict__ sqb, u16* __restrict__ skb)
{
    __shared__ u16 Als[BM * BK];
    __shared__ u16 Bls[BM * BK];
    __shared__ float ss[BM];

    const int tid  = threadIdx.x;
    const int lane = tid & 63;
    const int wave = tid >> 6;
    const int wm = wave >> 1;   // 2x2 wave grid, each wave 64x64
    const int wn = wave & 1;
    const int gm0 = blockIdx.y * BM;
    const int gn0 = blockIdx.x * BN;

    const int r0 = tid >> 2;
    const int qs = ((tid & 3) - ((tid >> 3) & 3)) & 3;   // source chunk index
    const int kc = qs * 8;                               // u16 offset within 32-elem k-slice
    const u16* gA0 = xb + (size_t)(gm0 + r0) * K_DIM + kc;
    const u16* gA1 = gA0 + (size_t)64 * K_DIM;
    const u16* gB0 = wb + (size_t)(gn0 + r0) * K_DIM + kc;
    const u16* gB1 = gB0 + (size_t)64 * K_DIM;
    char* lA0 = (char*)Als + wave * 1024;
    char* lA1 = (char*)Als + 4096 + wave * 1024;
    char* lB0 = (char*)Bls + wave * 1024;
    char* lB1 = (char*)Bls + 4096 + wave * 1024;

    f32x4 acc[4][4] = {};

    const int mr = lane & 15;
    const int q  = lane >> 4;
    const int s  = (q + (mr >> 1)) & 3;                  // swizzled read position
    const int fragoff = mr * 32 + s * 8;                 // u16 offset within 16-row group

    for (int kt = 0; kt < K_DIM / BK; ++kt) {
        GLL16(gA0, lA0); GLL16(gA1, lA1);
        GLL16(gB0, lB0); GLL16(gB1, lB1);
        gA0 += BK; gA1 += BK; gB0 += BK; gB1 += BK;
        __syncthreads();   // drains vmcnt(0) then barrier

        bf16x8 a[4], b[4];
#pragma unroll
        for (int i = 0; i < 4; ++i)
            a[i] = __builtin_bit_cast(bf16x8, *(const u16x8*)&Als[(wm * 4 + i) * 512 + fragoff]);
#pragma unroll
        for (int j = 0; j < 4; ++j)
            b[j] = __builtin_bit_cast(bf16x8, *(const u16x8*)&Bls[(wn * 4 + j) * 512 + fragoff]);
#pragma unroll
        for (int i = 0; i < 4; ++i)
#pragma unroll
            for (int j = 0; j < 4; ++j)
                acc[i][j] = __builtin_amdgcn_mfma_f32_16x16x32_bf16(a[i], b[j], acc[i][j], 0, 0, 0);
        __syncthreads();
    }

    // ---------------- epilogue ----------------
    const int which = gn0 >> 11;          // 0:q 1:k 2:sq 3:sk (block-uniform)
    if (tid < BM) ss[tid] = 0.0f;
    __syncthreads();

    const int mbase = wm * 64 + (lane >> 4) * 4;     // + i*16 + r
    const int col0  = (gn0 & 2047) + wn * 64 + (lane & 15);  // + j*16

    if (which < 2) {
        // per-row sum of squares over the tile's 128 cols (== one head, Dh=128)
#pragma unroll
        for (int i = 0; i < 4; ++i) {
#pragma unroll
            for (int r = 0; r < 4; ++r) {
                float sv = acc[i][0][r] * acc[i][0][r] + acc[i][1][r] * acc[i][1][r]
                         + acc[i][2][r] * acc[i][2][r] + acc[i][3][r] * acc[i][3][r];
                sv += __shfl_xor(sv, 1, 64);
                sv += __shfl_xor(sv, 2, 64);
                sv += __shfl_xor(sv, 4, 64);
                sv += __shfl_xor(sv, 8, 64);
                if ((lane & 15) == 0) atomicAdd(&ss[mbase + i * 16 + r], sv);
            }
        }
        __syncthreads();
    }

    u16* ob = (which == 0) ? qb : (which == 1) ? kb : (which == 2) ? sqb : skb;
#pragma unroll
    for (int i = 0; i < 4; ++i) {
#pragma unroll
        for (int r = 0; r < 4; ++r) {
            int m = mbase + i * 16 + r;
            size_t rowbase = (size_t)(gm0 + m) * 2048;
            float scale = 1.0f;
            if (which < 2)
                scale = rsqrtf(ss[m] * (1.0f / 128.0f) + 1.1920929e-07f);
#pragma unroll
            for (int j = 0; j < 4; ++j) {
                float v = acc[i][j][r];
                v = (which < 2) ? v * scale : softplus_f(v);
                ob[rowbase + col0 + j * 16] = f2bf(v);
            }
        }
    }
}

// ---------------- interp + multiply, 8 elems/thread, vectorized ----------------
// out[b,t,h,d] = interp(q, posq) * interp(k, posk);  layout [B*T, 2048]
// base is a multiple of 8 -> u16x8 loads (16B) and float4 stores are aligned, and a
// thread's 8 elems never cross a row (rows are 2048 wide).
__global__ void interp_mul(const u16* __restrict__ qb, const u16* __restrict__ kb,
                           const u16* __restrict__ sqb, const u16* __restrict__ skb,
                           float* __restrict__ out)
{
    size_t base = ((size_t)blockIdx.x * 256 + threadIdx.x) * 8;   // 16384 blocks: 2^22 threads * 8 = 2^25
    int c0 = (int)(base & 2047);
    size_t bt = base >> 11;
    int t = (int)(bt & 4095);
    float tf = (float)t;
    size_t rb = (base >> 23) << 23;   // b * T * 2048  (T*2048 = 2^23)

    u16x8 sqv8 = *(const u16x8*)&sqb[base];
    u16x8 skv8 = *(const u16x8*)&skb[base];

    float o[8];
#pragma unroll
    for (int e = 0; e < 8; ++e) {
        float sqv = bf2f(sqv8[e]);
        float skv = bf2f(skv8[e]);
        float pq = fminf(fmaxf(tf - sqv, 0.0f), tf);
        float pk = fminf(fmaxf(tf - skv, 0.0f), tf);
        float pqf = floorf(pq), pkf = floorf(pk);
        int q0i = (int)pqf, k0i = (int)pkf;
        int q1i = min(q0i + 1, 4095), k1i = min(k0i + 1, 4095);
        float fq = pq - pqf, fk = pk - pkf;
        size_t oo = rb + (size_t)(c0 + e);
        float q0 = bf2f(qb[oo + ((size_t)q0i << 11)]);
        float q1 = bf2f(qb[oo + ((size_t)q1i << 11)]);
        float k0 = bf2f(kb[oo + ((size_t)k0i << 11)]);
        float k1 = bf2f(kb[oo + ((size_t)k1i << 11)]);
        float qd = q0 + (q1 - q0) * fq;
        float kd = k0 + (k1 - k0) * fk;
        o[e] = qd * kd;
    }
    float4 lo = make_float4(o[0], o[1], o[2], o[3]);
    float4 hi = make_float4(o[4], o[5], o[6], o[7]);
    float4* op = (float4*)&out[base];
    op[0] = lo;
    op[1] = hi;
}

extern "C" void kernel_launch(void* const* d_in, const int* in_sizes, int n_in,
                              void* d_out, int out_size, void* d_ws, size_t ws_size,
                              hipStream_t stream) {
    const float* x   = (const float*)d_in[0];
    const float* Wq  = (const float*)d_in[1];
    const float* Wk  = (const float*)d_in[2];
    const float* Wsq = (const float*)d_in[3];
    const float* Wsk = (const float*)d_in[4];
    float* out = (float*)d_out;

    // ws layout (bytes): xb 64MB | wb 32MB | qb 64MB | kb 64MB | sqb 64MB | skb 64MB = 352MB
    const size_t NEED = 369098752;
    if (ws_size < NEED) return;   // loud failure -> ws too small
    char* ws = (char*)d_ws;
    u16* xb  = (u16*)(ws);
    u16* wb  = (u16*)(ws + 67108864);
    u16* qb  = (u16*)(ws + 100663296);
    u16* kb  = (u16*)(ws + 167772160);
    u16* sqb = (u16*)(ws + 234881024);
    u16* skb = (u16*)(ws + 301989888);

    pack_kernel<<<32768, 256, 0, stream>>>(x, xb, 8388608);
    dim3 wgrid(4096, 4);
    pack4_kernel<<<wgrid, 256, 0, stream>>>(Wq, Wk, Wsq, Wsk, wb);

    dim3 ggrid(64, 128);   // N tiles x M tiles
    gemm_fused<<<ggrid, 256, 0, stream>>>(xb, wb, qb, kb, sqb, skb);

    interp_mul<<<16384, 256, 0, stream>>>(qb, kb, sqb, skb, out);
}